// Round 5
// baseline (159.927 us; speedup 1.0000x reference)
//
#include <hip/hip_runtime.h>

typedef unsigned short u16;
typedef unsigned int   u32;
typedef __bf16 bf16x8 __attribute__((ext_vector_type(8)));
typedef float  f32x4  __attribute__((ext_vector_type(4)));
typedef u16    u16x8  __attribute__((ext_vector_type(8)));
typedef u16    u16x4  __attribute__((ext_vector_type(4)));

__device__ __forceinline__ float b2f(u16 h) {
  return __builtin_bit_cast(float, ((u32)h) << 16);
}
__device__ __forceinline__ u16 f2b(float f) {
  u32 u = __builtin_bit_cast(u32, f);
  u32 r = u + 0x7FFFu + ((u >> 16) & 1u);
  return (u16)(r >> 16);
}

#define GLD_AS1(p) ((const __attribute__((address_space(1))) void*)(p))
#define LDS_AS3(p) ((__attribute__((address_space(3))) void*)(p))

// ---------------------------------------------------------------------------
// GEMM1 + fused softmax + IN-EPILOGUE context partials (R3-proven epilogue:
// private ctxp[p][bh][4096] stores, NO atomics).
// K-loop: 3-buffer counted-vmcnt pipeline.
// ---------------------------------------------------------------------------
__global__ void gemm_qkv_kernel(const u16* __restrict__ A, const u16* __restrict__ Bt,
                                u16* __restrict__ qb, float* __restrict__ ctxp) {
  const int K = 512;
  __shared__ u16 smem[24576];  // 3 x (As 8KB + Bs 8KB) = 48 KB; T aliases [0,18KB)
  const int id = blockIdx.x;
  const int tn = id >> 7;
  const int tm = (id & 7) * 16 + ((id >> 3) & 15);
  const int tileM = tm * 128;
  const int t = threadIdx.x;
  const int lane = t & 63;
  const int wave = t >> 6;
  const int mbase = (wave >> 1) * 64;
  const int nbase = (wave & 1) * 64;
  const int fm = lane & 15;
  const int kg = lane >> 4;
  const bool is_q = (tn < 4);
  const int j = tn - 4;

  f32x4 acc[4][4];
#pragma unroll
  for (int i = 0; i < 4; ++i)
#pragma unroll
    for (int jj = 0; jj < 4; ++jj) acc[i][jj] = (f32x4){0.f, 0.f, 0.f, 0.f};

  auto stage = [&](int buf, int k0) {
    u16* As = smem + buf * 8192;
    u16* Bs = As + 4096;
#pragma unroll
    for (int p = 0; p < 2; ++p) {
      int c = p * 256 + t;
      int r = c >> 2;
      int g = (c & 3) ^ ((r >> 1) & 3);
      const u16* ga = A + (size_t)(tileM + r) * K + (k0 + g * 8);
      __builtin_amdgcn_global_load_lds(GLD_AS1(ga), LDS_AS3(As + c * 8), 16, 0, 0);
      int brow = is_q ? (tn * 128 + r) : (512 + j * 64 + r + (r >> 6) * 448);
      const u16* gb = Bt + (size_t)brow * K + (k0 + g * 8);
      __builtin_amdgcn_global_load_lds(GLD_AS1(gb), LDS_AS3(Bs + c * 8), 16, 0, 0);
    }
  };

  stage(0, 0);     // 4 loads/thread per stage
  stage(1, 32);
  stage(2, 64);

  int cur = 0;
  for (int kk = 0; kk < 16; ++kk) {
    if (kk <= 13)      asm volatile("s_waitcnt vmcnt(8)" ::: "memory");
    else if (kk == 14) asm volatile("s_waitcnt vmcnt(4)" ::: "memory");
    else               asm volatile("s_waitcnt vmcnt(0)" ::: "memory");
    __builtin_amdgcn_s_barrier();   // all waves' tile-kk loads landed

    const u16* As = smem + cur * 8192;
    const u16* Bs = As + 4096;
    bf16x8 af[4], bfr[4];
#pragma unroll
    for (int mi = 0; mi < 4; ++mi) {
      int m = mbase + mi * 16 + fm;
      int sg = kg ^ ((m >> 1) & 3);
      af[mi] = *(const bf16x8*)(As + m * 32 + sg * 8);
    }
#pragma unroll
    for (int ni = 0; ni < 4; ++ni) {
      int n = nbase + ni * 16 + fm;
      int sg = kg ^ ((n >> 1) & 3);
      bfr[ni] = *(const bf16x8*)(Bs + n * 32 + sg * 8);
    }
    asm volatile("s_waitcnt lgkmcnt(0)" ::: "memory");  // my reads in VGPRs
    __builtin_amdgcn_sched_barrier(0);
    __builtin_amdgcn_s_barrier();   // ALL waves done reading buf cur

    if (kk <= 12) stage(cur, (kk + 3) * 32);  // overwrite just-read buffer

#pragma unroll
    for (int mi = 0; mi < 4; ++mi)
#pragma unroll
      for (int ni = 0; ni < 4; ++ni)
        acc[mi][ni] = __builtin_amdgcn_mfma_f32_16x16x32_bf16(af[mi], bfr[ni],
                                                              acc[mi][ni], 0, 0, 0);
    cur = (cur == 2) ? 0 : cur + 1;
  }

  const int rq = lane >> 4;

  float inv[4][4];
  const bool do_sm = is_q || ((wave & 1) == 0);
  if (do_sm) {
#pragma unroll
    for (int mi = 0; mi < 4; ++mi)
#pragma unroll
      for (int ni = 0; ni < 4; ++ni)
#pragma unroll
        for (int reg = 0; reg < 4; ++reg)
          acc[mi][ni][reg] = __expf(acc[mi][ni][reg]);
#pragma unroll
    for (int mi = 0; mi < 4; ++mi)
#pragma unroll
      for (int reg = 0; reg < 4; ++reg) {
        float s = acc[mi][0][reg] + acc[mi][1][reg] + acc[mi][2][reg] + acc[mi][3][reg];
        s += __shfl_xor(s, 1);
        s += __shfl_xor(s, 2);
        s += __shfl_xor(s, 4);
        s += __shfl_xor(s, 8);
        inv[mi][reg] = 1.f / s;
      }
  } else {
#pragma unroll
    for (int mi = 0; mi < 4; ++mi)
#pragma unroll
      for (int reg = 0; reg < 4; ++reg) inv[mi][reg] = 1.f;
  }

  if (is_q) {
#pragma unroll
    for (int mi = 0; mi < 4; ++mi)
#pragma unroll
      for (int ni = 0; ni < 4; ++ni)
#pragma unroll
        for (int reg = 0; reg < 4; ++reg) {
          int gr = tileM + mbase + mi * 16 + rq * 4 + reg;
          int gc = tn * 128 + nbase + ni * 16 + fm;
          qb[(size_t)gr * 512 + gc] = f2b(acc[mi][ni][reg] * inv[mi][reg]);
        }
    return;
  }

  u16* T = smem;
  f32x4 cacc[4];
#pragma unroll
  for (int i = 0; i < 4; ++i) cacc[i] = (f32x4){0.f, 0.f, 0.f, 0.f};

#pragma unroll
  for (int ph = 0; ph < 2; ++ph) {
    if ((wave >> 1) == ph) {
#pragma unroll
      for (int mi = 0; mi < 4; ++mi)
#pragma unroll
        for (int ni = 0; ni < 4; ++ni) {
          u16x4 o;
#pragma unroll
          for (int reg = 0; reg < 4; ++reg)
            o[reg] = f2b(acc[mi][ni][reg] * inv[mi][reg]);
          int c = nbase + ni * 16 + fm;
          *(u16x4*)(T + c * 72 + mi * 16 + rq * 4) = o;
        }
    }
    __syncthreads();
#pragma unroll
    for (int kk = 0; kk < 2; ++kk) {
      bf16x8 afc = *(const bf16x8*)(T + (wave * 16 + fm) * 72 + kk * 32 + kg * 8);
#pragma unroll
      for (int et = 0; et < 4; ++et) {
        bf16x8 bfc = *(const bf16x8*)(T + (64 + et * 16 + fm) * 72 + kk * 32 + kg * 8);
        cacc[et] = __builtin_amdgcn_mfma_f32_16x16x32_bf16(afc, bfc, cacc[et], 0, 0, 0);
      }
    }
    __syncthreads();
  }

  const int b = tm >> 5;
  const int s = tm & 31;
  float* cp = ctxp + ((size_t)s * 32 + b * 8 + j) * 4096;
#pragma unroll
  for (int et = 0; et < 4; ++et)
#pragma unroll
    for (int reg = 0; reg < 4; ++reg)
      cp[(wave * 16 + rq * 4 + reg) * 64 + et * 16 + fm] = cacc[et][reg];
}

// ---------------------------------------------------------------------------
// prep_all: [0,4096) cast x; [4096,4288) Wt tiles; [4288,4352) Wot tiles.
// ---------------------------------------------------------------------------
__global__ void prep_all_kernel(const float* __restrict__ x, const float* __restrict__ Wq,
                                const float* __restrict__ Wk, const float* __restrict__ Wv,
                                const float* __restrict__ Wo, u16* __restrict__ xb,
                                u16* __restrict__ Wt, u16* __restrict__ Wot) {
  __shared__ u16 tr[64 * 72];
  const int id = blockIdx.x;
  const int t = threadIdx.x;

  if (id < 4096) {
    int i = (id * 256 + t) * 8;
    float4 a = *(const float4*)(x + i);
    float4 b = *(const float4*)(x + i + 4);
    u16x8 o;
    o[0] = f2b(a.x); o[1] = f2b(a.y); o[2] = f2b(a.z); o[3] = f2b(a.w);
    o[4] = f2b(b.x); o[5] = f2b(b.y); o[6] = f2b(b.z); o[7] = f2b(b.w);
    *(u16x8*)(xb + i) = o;
    return;
  }
  const float* W;
  u16* dst;
  int n0, k0;
  if (id < 4288) {
    int tile = id - 4096;
    n0 = (tile >> 3) * 64;
    k0 = (tile & 7) * 64;
    W = (n0 < 512) ? Wq : ((n0 < 1024) ? Wk : Wv);
    dst = Wt;
  } else {
    int tile = id - 4288;
    n0 = (tile >> 3) * 64;
    k0 = (tile & 7) * 64;
    W = Wo;
    dst = Wot;
  }
  int cin = (n0 & 511);
  int c = t & 63;
  int r0 = t >> 6;
#pragma unroll
  for (int i = 0; i < 16; ++i) {
    int r = r0 * 16 + i;
    tr[c * 72 + r] = f2b(W[(size_t)(k0 + r) * 512 + cin + c]);
  }
  __syncthreads();
#pragma unroll
  for (int jj = 0; jj < 2; ++jj) {
    int idx = jj * 256 + t;
    int row = idx >> 3;
    int seg = idx & 7;
    u16x8 val = *(const u16x8*)(tr + row * 72 + seg * 8);
    *(u16x8*)(dst + (size_t)(n0 + row) * 512 + k0 + seg * 8) = val;
  }
}

// ---------------------------------------------------------------------------
// ctxm FUSED with reduction: per (bh,cq) block, sum the 32 ctxp partials for
// this head (deterministic, coalesced 16B/lane), bf16-ize into LDS, then
// Mt[b][c][h*64+d] = sum_e Wot[c][h*64+e] * ctx_h[d][e]  (MFMA K=64).
// Replaces the former ctx_reduce kernel + ctxb intermediate (one fewer launch).
// ---------------------------------------------------------------------------
__global__ void ctxm_kernel(const float* __restrict__ ctxp, const u16* __restrict__ Wot,
                            u16* __restrict__ Mt) {
  __shared__ u16 ctxd[64 * 72];
  const int id = blockIdx.x;
  const int bh = id >> 2;
  const int cq = id & 3;
  const int b = bh >> 3, h = bh & 7;
  const int t = threadIdx.x;
  const int lane = t & 63;
  const int wave = t >> 6;
  const int fm = lane & 15;
  const int kg = lane >> 4;
  const int rq = lane >> 4;

  {
    f32x4 s0 = (f32x4){0.f, 0.f, 0.f, 0.f};
    f32x4 s1 = s0, s2 = s0, s3 = s0;
    const float* base = ctxp + (size_t)bh * 4096 + t * 4;
#pragma unroll 4
    for (int p = 0; p < 32; ++p) {
      const float* src = base + (size_t)p * 32 * 4096;
      s0 += *(const f32x4*)(src);
      s1 += *(const f32x4*)(src + 1024);
      s2 += *(const f32x4*)(src + 2048);
      s3 += *(const f32x4*)(src + 3072);
    }
    f32x4 ss[4] = {s0, s1, s2, s3};
#pragma unroll
    for (int q = 0; q < 4; ++q) {
      int idx = t * 4 + q * 1024;
      int d = idx >> 6, e = idx & 63;
      u16x4 o;
      o[0] = f2b(ss[q][0]); o[1] = f2b(ss[q][1]);
      o[2] = f2b(ss[q][2]); o[3] = f2b(ss[q][3]);
      *(u16x4*)(ctxd + d * 72 + e) = o;
    }
  }
  __syncthreads();

  f32x4 acc[2][4];
#pragma unroll
  for (int i = 0; i < 2; ++i)
#pragma unroll
    for (int jj = 0; jj < 4; ++jj) acc[i][jj] = (f32x4){0.f, 0.f, 0.f, 0.f};

#pragma unroll
  for (int ks = 0; ks < 2; ++ks) {
    bf16x8 bfr[4];
#pragma unroll
    for (int dt = 0; dt < 4; ++dt)
      bfr[dt] = *(const bf16x8*)(ctxd + (dt * 16 + fm) * 72 + ks * 32 + kg * 8);
#pragma unroll
    for (int mi = 0; mi < 2; ++mi) {
      int c = cq * 128 + wave * 32 + mi * 16 + fm;
      bf16x8 af = *(const bf16x8*)(Wot + (size_t)c * 512 + h * 64 + ks * 32 + kg * 8);
#pragma unroll
      for (int dt = 0; dt < 4; ++dt)
        acc[mi][dt] = __builtin_amdgcn_mfma_f32_16x16x32_bf16(af, bfr[dt],
                                                              acc[mi][dt], 0, 0, 0);
    }
  }

  u16* mb = Mt + (size_t)b * 512 * 512;
#pragma unroll
  for (int mi = 0; mi < 2; ++mi)
#pragma unroll
    for (int dt = 0; dt < 4; ++dt)
#pragma unroll
      for (int reg = 0; reg < 4; ++reg) {
        int c = cq * 128 + wave * 32 + mi * 16 + rq * 4 + reg;
        mb[(size_t)c * 512 + h * 64 + dt * 16 + fm] = f2b(acc[mi][dt][reg]);
      }
}

// ---------------------------------------------------------------------------
// Final GEMM: out[b] = q'[b] @ Mt[b]^T + bo. 64x128 tiles, grid 1024.
// Counted-vmcnt 3-buffer pipeline (unchanged from R3).
// ---------------------------------------------------------------------------
__global__ void gemm_out_kernel(const u16* __restrict__ A, const u16* __restrict__ Mt,
                                float* __restrict__ Cout, const float* __restrict__ bias) {
  const int K = 512, N = 512;
  __shared__ u16 smem[18432];  // 3 x (As 4KB + Bs 8KB) = 36 KB
  const int id = blockIdx.x;
  const int tn = id >> 8;                              // [0,4): 128-col tiles
  const int tm = (id & 7) * 32 + ((id >> 3) & 31);     // [0,256): 64-row tiles
  const int tileN = tn * 128;
  const int tileM = tm * 64;
  const u16* Bt = Mt + (size_t)(tm >> 6) * 512 * 512;  // batch = tm/64
  const int t = threadIdx.x;
  const int lane = t & 63;
  const int wave = t >> 6;
  const int mbase = (wave >> 1) * 32;
  const int nbase = (wave & 1) * 64;
  const int fm = lane & 15;
  const int kg = lane >> 4;

  f32x4 acc[2][4];
#pragma unroll
  for (int i = 0; i < 2; ++i)
#pragma unroll
    for (int jj = 0; jj < 4; ++jj) acc[i][jj] = (f32x4){0.f, 0.f, 0.f, 0.f};

  auto stage = [&](int buf, int k0) {
    u16* As = smem + buf * 6144;
    u16* Bs = As + 2048;
    {
      int c = t;                      // A: 64 rows x 4 groups = 256 chunks
      int r = c >> 2;
      int g = (c & 3) ^ ((r >> 1) & 3);
      const u16* ga = A + (size_t)(tileM + r) * K + (k0 + g * 8);
      __builtin_amdgcn_global_load_lds(GLD_AS1(ga), LDS_AS3(As + c * 8), 16, 0, 0);
    }
#pragma unroll
    for (int p = 0; p < 2; ++p) {
      int c = p * 256 + t;            // B: 128 rows x 4 groups = 512 chunks
      int r = c >> 2;
      int g = (c & 3) ^ ((r >> 1) & 3);
      const u16* gb = Bt + (size_t)(tileN + r) * K + (k0 + g * 8);
      __builtin_amdgcn_global_load_lds(GLD_AS1(gb), LDS_AS3(Bs + c * 8), 16, 0, 0);
    }
  };

  stage(0, 0);     // 3 loads/thread per stage
  stage(1, 32);
  stage(2, 64);

  int cur = 0;
  for (int kk = 0; kk < 16; ++kk) {
    if (kk <= 13)      asm volatile("s_waitcnt vmcnt(6)" ::: "memory");
    else if (kk == 14) asm volatile("s_waitcnt vmcnt(3)" ::: "memory");
    else               asm volatile("s_waitcnt vmcnt(0)" ::: "memory");
    __builtin_amdgcn_s_barrier();

    const u16* As = smem + cur * 6144;
    const u16* Bs = As + 2048;
    bf16x8 af[2], bfr[4];
#pragma unroll
    for (int mi = 0; mi < 2; ++mi) {
      int m = mbase + mi * 16 + fm;
      int sg = kg ^ ((m >> 1) & 3);
      af[mi] = *(const bf16x8*)(As + m * 32 + sg * 8);
    }
#pragma unroll
    for (int ni = 0; ni < 4; ++ni) {
      int n = nbase + ni * 16 + fm;
      int sg = kg ^ ((n >> 1) & 3);
      bfr[ni] = *(const bf16x8*)(Bs + n * 32 + sg * 8);
    }
    asm volatile("s_waitcnt lgkmcnt(0)" ::: "memory");
    __builtin_amdgcn_sched_barrier(0);
    __builtin_amdgcn_s_barrier();

    if (kk <= 12) stage(cur, (kk + 3) * 32);

#pragma unroll
    for (int mi = 0; mi < 2; ++mi)
#pragma unroll
      for (int ni = 0; ni < 4; ++ni)
        acc[mi][ni] = __builtin_amdgcn_mfma_f32_16x16x32_bf16(af[mi], bfr[ni],
                                                              acc[mi][ni], 0, 0, 0);
    cur = (cur == 2) ? 0 : cur + 1;
  }

  const int rq = lane >> 4;
#pragma unroll
  for (int mi = 0; mi < 2; ++mi)
#pragma unroll
    for (int ni = 0; ni < 4; ++ni)
#pragma unroll
      for (int reg = 0; reg < 4; ++reg) {
        int gr = tileM + mbase + mi * 16 + rq * 4 + reg;
        int gc = tileN + nbase + ni * 16 + fm;
        Cout[(size_t)gr * N + gc] = acc[mi][ni][reg] + bias[gc];
      }
}

// ---------------------------------------------------------------------------
extern "C" void kernel_launch(void* const* d_in, const int* in_sizes, int n_in,
                              void* d_out, int out_size, void* d_ws, size_t ws_size,
                              hipStream_t stream) {
  const float* x  = (const float*)d_in[0];
  const float* Wq = (const float*)d_in[1];
  const float* Wk = (const float*)d_in[2];
  const float* Wv = (const float*)d_in[3];
  const float* Wo = (const float*)d_in[4];
  const float* bo = (const float*)d_in[5];

  char* w = (char*)d_ws;
  u16* xb   = (u16*)w;    w += (size_t)16384 * 512 * 2;     // 16.8 MB
  u16* Wt   = (u16*)w;    w += (size_t)1536 * 512 * 2;      // 1.6 MB
  u16* Wot  = (u16*)w;    w += (size_t)512 * 512 * 2;       // 0.5 MB
  u16* qbuf = (u16*)w;    w += (size_t)16384 * 512 * 2;     // 16.8 MB
  float* ctxp = (float*)w; w += (size_t)32 * 32 * 4096 * 4; // 16.8 MB
  u16* Mt   = (u16*)w;    w += (size_t)4 * 512 * 512 * 2;   // 2.1 MB

  prep_all_kernel<<<4352, 256, 0, stream>>>(x, Wq, Wk, Wv, Wo, xb, Wt, Wot);
  gemm_qkv_kernel<<<1536, 256, 0, stream>>>(xb, Wt, qbuf, ctxp);
  ctxm_kernel<<<128, 256, 0, stream>>>(ctxp, Wot, Mt);
  gemm_out_kernel<<<1024, 256, 0, stream>>>(qbuf, Mt, (float*)d_out, bo);
}

// Round 6
// 152.963 us; speedup vs baseline: 1.0455x; 1.0455x over previous
//
#include <hip/hip_runtime.h>

typedef unsigned short u16;
typedef unsigned int   u32;
typedef __bf16 bf16x8 __attribute__((ext_vector_type(8)));
typedef float  f32x4  __attribute__((ext_vector_type(4)));
typedef u16    u16x8  __attribute__((ext_vector_type(8)));
typedef u16    u16x4  __attribute__((ext_vector_type(4)));

__device__ __forceinline__ float b2f(u16 h) {
  return __builtin_bit_cast(float, ((u32)h) << 16);
}
__device__ __forceinline__ u16 f2b(float f) {
  u32 u = __builtin_bit_cast(u32, f);
  u32 r = u + 0x7FFFu + ((u >> 16) & 1u);
  return (u16)(r >> 16);
}

#define GLD_AS1(p) ((const __attribute__((address_space(1))) void*)(p))
#define LDS_AS3(p) ((__attribute__((address_space(3))) void*)(p))

// ---------------------------------------------------------------------------
// GEMM1 + fused softmax + IN-EPILOGUE context partials.
// RETILED for LDS-port intensity: 256x128 block, 4 waves each owning 128x64
// (8 A-frags + 4 B-frags -> 32 MFMA = 44 FLOP/LDS-byte, vs 32 before).
// MfmaUtil was pinned at ~21% == measured LDS-port ceiling of the old 64x64
// wave tile. K-loop keeps the 3-buffer counted-vmcnt pipeline (6 loads/thread
// per stage -> vmcnt 12/6/0).
// ---------------------------------------------------------------------------
__global__ __launch_bounds__(256, 2)
void gemm_qkv_kernel(const u16* __restrict__ A, const u16* __restrict__ Bt,
                     u16* __restrict__ qb, float* __restrict__ ctxp) {
  const int K = 512;
  __shared__ u16 smem[36864];  // 3 x (As 16KB + Bs 8KB) = 72 KB; T aliases 18KB
  const int id = blockIdx.x;
  const int tn = id >> 6;                            // [0,12): 128-col tiles
  const int tm = (id & 7) * 8 + ((id >> 3) & 7);     // [0,64): 256-row tiles, XCD swz
  const int tileM = tm * 256;
  const int t = threadIdx.x;
  const int lane = t & 63;
  const int wave = t >> 6;
  const int mbase = (wave >> 1) * 128;
  const int nbase = (wave & 1) * 64;
  const int fm = lane & 15;
  const int kg = lane >> 4;
  const bool is_q = (tn < 4);
  const int j = tn - 4;

  f32x4 acc[8][4];
#pragma unroll
  for (int i = 0; i < 8; ++i)
#pragma unroll
    for (int jj = 0; jj < 4; ++jj) acc[i][jj] = (f32x4){0.f, 0.f, 0.f, 0.f};

  auto stage = [&](int buf, int k0) {
    u16* As = smem + buf * 12288;
    u16* Bs = As + 8192;
#pragma unroll
    for (int p = 0; p < 4; ++p) {            // A: 256 rows x 4 groups = 1024 chunks
      int c = p * 256 + t;
      int r = c >> 2;
      int g = (c & 3) ^ ((r >> 1) & 3);
      const u16* ga = A + (size_t)(tileM + r) * K + (k0 + g * 8);
      __builtin_amdgcn_global_load_lds(GLD_AS1(ga), LDS_AS3(As + c * 8), 16, 0, 0);
    }
#pragma unroll
    for (int p = 0; p < 2; ++p) {            // B: 128 rows x 4 groups = 512 chunks
      int c = p * 256 + t;
      int r = c >> 2;
      int g = (c & 3) ^ ((r >> 1) & 3);
      int brow = is_q ? (tn * 128 + r) : (512 + j * 64 + r + (r >> 6) * 448);
      const u16* gb = Bt + (size_t)brow * K + (k0 + g * 8);
      __builtin_amdgcn_global_load_lds(GLD_AS1(gb), LDS_AS3(Bs + c * 8), 16, 0, 0);
    }
  };

  stage(0, 0);     // 6 loads/thread per stage
  stage(1, 32);
  stage(2, 64);

  int cur = 0;
  for (int kk = 0; kk < 16; ++kk) {
    if (kk <= 13)      asm volatile("s_waitcnt vmcnt(12)" ::: "memory");
    else if (kk == 14) asm volatile("s_waitcnt vmcnt(6)" ::: "memory");
    else               asm volatile("s_waitcnt vmcnt(0)" ::: "memory");
    __builtin_amdgcn_s_barrier();   // all waves' tile-kk loads landed

    const u16* As = smem + cur * 12288;
    const u16* Bs = As + 8192;
    bf16x8 af[8], bfr[4];
#pragma unroll
    for (int mi = 0; mi < 8; ++mi) {
      int m = mbase + mi * 16 + fm;
      int sg = kg ^ ((m >> 1) & 3);
      af[mi] = *(const bf16x8*)(As + m * 32 + sg * 8);
    }
#pragma unroll
    for (int ni = 0; ni < 4; ++ni) {
      int n = nbase + ni * 16 + fm;
      int sg = kg ^ ((n >> 1) & 3);
      bfr[ni] = *(const bf16x8*)(Bs + n * 32 + sg * 8);
    }
    asm volatile("s_waitcnt lgkmcnt(0)" ::: "memory");  // my reads in VGPRs
    __builtin_amdgcn_sched_barrier(0);
    __builtin_amdgcn_s_barrier();   // ALL waves done reading buf cur

    if (kk <= 12) stage(cur, (kk + 3) * 32);  // overwrite just-read buffer

#pragma unroll
    for (int mi = 0; mi < 8; ++mi)
#pragma unroll
      for (int ni = 0; ni < 4; ++ni)
        acc[mi][ni] = __builtin_amdgcn_mfma_f32_16x16x32_bf16(af[mi], bfr[ni],
                                                              acc[mi][ni], 0, 0, 0);
    cur = (cur == 2) ? 0 : cur + 1;
  }

  const int rq = lane >> 4;

  // Wave-local softmax over this wave's 64-col head span (4 ni-frags).
  float inv[8][4];
  const bool do_sm = is_q || ((wave & 1) == 0);
  if (do_sm) {
#pragma unroll
    for (int mi = 0; mi < 8; ++mi)
#pragma unroll
      for (int ni = 0; ni < 4; ++ni)
#pragma unroll
        for (int reg = 0; reg < 4; ++reg)
          acc[mi][ni][reg] = __expf(acc[mi][ni][reg]);
#pragma unroll
    for (int mi = 0; mi < 8; ++mi)
#pragma unroll
      for (int reg = 0; reg < 4; ++reg) {
        float s = acc[mi][0][reg] + acc[mi][1][reg] + acc[mi][2][reg] + acc[mi][3][reg];
        s += __shfl_xor(s, 1);
        s += __shfl_xor(s, 2);
        s += __shfl_xor(s, 4);
        s += __shfl_xor(s, 8);
        inv[mi][reg] = 1.f / s;
      }
  } else {
#pragma unroll
    for (int mi = 0; mi < 8; ++mi)
#pragma unroll
      for (int reg = 0; reg < 4; ++reg) inv[mi][reg] = 1.f;
  }

  if (is_q) {
#pragma unroll
    for (int mi = 0; mi < 8; ++mi)
#pragma unroll
      for (int ni = 0; ni < 4; ++ni)
#pragma unroll
        for (int reg = 0; reg < 4; ++reg) {
          int gr = tileM + mbase + mi * 16 + rq * 4 + reg;
          int gc = tn * 128 + nbase + ni * 16 + fm;
          qb[(size_t)gr * 512 + gc] = f2b(acc[mi][ni][reg] * inv[mi][reg]);
        }
    return;
  }

  // ctx partial: P^T V over this block's 256 rows, via 4 transpose phases of
  // 64 rows. Phase ph: waves (wave>>1)==(ph>>1) write their mi-half (ph&1).
  u16* T = smem;   // [128 cols][72] u16 = 18 KB, aliases buf0 (K-loop done)
  f32x4 cacc[4];
#pragma unroll
  for (int i = 0; i < 4; ++i) cacc[i] = (f32x4){0.f, 0.f, 0.f, 0.f};

#pragma unroll
  for (int ph = 0; ph < 4; ++ph) {
    if ((wave >> 1) == (ph >> 1)) {
#pragma unroll
      for (int mi2 = 0; mi2 < 4; ++mi2) {
        int mi = (ph & 1) * 4 + mi2;
#pragma unroll
        for (int ni = 0; ni < 4; ++ni) {
          u16x4 o;
#pragma unroll
          for (int reg = 0; reg < 4; ++reg)
            o[reg] = f2b(acc[mi][ni][reg] * inv[mi][reg]);
          int c = nbase + ni * 16 + fm;
          *(u16x4*)(T + c * 72 + mi2 * 16 + rq * 4) = o;
        }
      }
    }
    __syncthreads();
#pragma unroll
    for (int kc = 0; kc < 2; ++kc) {
      bf16x8 afc = *(const bf16x8*)(T + (wave * 16 + fm) * 72 + kc * 32 + kg * 8);
#pragma unroll
      for (int et = 0; et < 4; ++et) {
        bf16x8 bfc = *(const bf16x8*)(T + (64 + et * 16 + fm) * 72 + kc * 32 + kg * 8);
        cacc[et] = __builtin_amdgcn_mfma_f32_16x16x32_bf16(afc, bfc, cacc[et], 0, 0, 0);
      }
    }
    __syncthreads();
  }

  const int b = tm >> 4;        // 16 row-tiles per batch
  const int s = tm & 15;        // 16 partial slots
  float* cp = ctxp + ((size_t)s * 32 + b * 8 + j) * 4096;
#pragma unroll
  for (int et = 0; et < 4; ++et)
#pragma unroll
    for (int reg = 0; reg < 4; ++reg)
      cp[(wave * 16 + rq * 4 + reg) * 64 + et * 16 + fm] = cacc[et][reg];
}

// ---------------------------------------------------------------------------
// prep_all: [0,4096) cast x; [4096,4288) Wt tiles; [4288,4352) Wot tiles.
// ---------------------------------------------------------------------------
__global__ void prep_all_kernel(const float* __restrict__ x, const float* __restrict__ Wq,
                                const float* __restrict__ Wk, const float* __restrict__ Wv,
                                const float* __restrict__ Wo, u16* __restrict__ xb,
                                u16* __restrict__ Wt, u16* __restrict__ Wot) {
  __shared__ u16 tr[64 * 72];
  const int id = blockIdx.x;
  const int t = threadIdx.x;

  if (id < 4096) {
    int i = (id * 256 + t) * 8;
    float4 a = *(const float4*)(x + i);
    float4 b = *(const float4*)(x + i + 4);
    u16x8 o;
    o[0] = f2b(a.x); o[1] = f2b(a.y); o[2] = f2b(a.z); o[3] = f2b(a.w);
    o[4] = f2b(b.x); o[5] = f2b(b.y); o[6] = f2b(b.z); o[7] = f2b(b.w);
    *(u16x8*)(xb + i) = o;
    return;
  }
  const float* W;
  u16* dst;
  int n0, k0;
  if (id < 4288) {
    int tile = id - 4096;
    n0 = (tile >> 3) * 64;
    k0 = (tile & 7) * 64;
    W = (n0 < 512) ? Wq : ((n0 < 1024) ? Wk : Wv);
    dst = Wt;
  } else {
    int tile = id - 4288;
    n0 = (tile >> 3) * 64;
    k0 = (tile & 7) * 64;
    W = Wo;
    dst = Wot;
  }
  int cin = (n0 & 511);
  int c = t & 63;
  int r0 = t >> 6;
#pragma unroll
  for (int i = 0; i < 16; ++i) {
    int r = r0 * 16 + i;
    tr[c * 72 + r] = f2b(W[(size_t)(k0 + r) * 512 + cin + c]);
  }
  __syncthreads();
#pragma unroll
  for (int jj = 0; jj < 2; ++jj) {
    int idx = jj * 256 + t;
    int row = idx >> 3;
    int seg = idx & 7;
    u16x8 val = *(const u16x8*)(tr + row * 72 + seg * 8);
    *(u16x8*)(dst + (size_t)(n0 + row) * 512 + k0 + seg * 8) = val;
  }
}

// ---------------------------------------------------------------------------
// ctx_reduce: WIDE reduction over 16 partial slots. Grid 128.
// ---------------------------------------------------------------------------
__global__ void ctx_reduce_kernel(const float* __restrict__ ctxp, u16* __restrict__ ctxb) {
  const int id = blockIdx.x;
  const int bh = id >> 2;
  const int chunk = id & 3;
  const int t = threadIdx.x;
  const int idx = chunk * 1024 + t * 4;
  f32x4 s = (f32x4){0.f, 0.f, 0.f, 0.f};
#pragma unroll
  for (int p = 0; p < 16; ++p)
    s += *(const f32x4*)(ctxp + ((size_t)p * 32 + bh) * 4096 + idx);
  u16x4 o;
#pragma unroll
  for (int jj = 0; jj < 4; ++jj) o[jj] = f2b(s[jj]);
  *(u16x4*)(ctxb + (size_t)bh * 4096 + idx) = o;
}

// ---------------------------------------------------------------------------
// ctxm_mfma: Mt[b][c][h*64+d] = sum_e Wot[c][h*64+e] * ctx_h[d][e].
// ---------------------------------------------------------------------------
__global__ void ctxm_kernel(const u16* __restrict__ ctxb, const u16* __restrict__ Wot,
                            u16* __restrict__ Mt) {
  __shared__ u16 ctxd[64 * 72];
  const int id = blockIdx.x;
  const int bh = id >> 2;
  const int cq = id & 3;
  const int b = bh >> 3, h = bh & 7;
  const int t = threadIdx.x;
  const int lane = t & 63;
  const int wave = t >> 6;
  const int fm = lane & 15;
  const int kg = lane >> 4;
  const int rq = lane >> 4;

  {
    int base = t * 16;                 // 256 thr x 16 elems = 4096
    int d = base >> 6, e = base & 63;
    u16x8 v0 = *(const u16x8*)(ctxb + (size_t)bh * 4096 + base);
    u16x8 v1 = *(const u16x8*)(ctxb + (size_t)bh * 4096 + base + 8);
    *(u16x8*)(ctxd + d * 72 + e) = v0;
    *(u16x8*)(ctxd + d * 72 + e + 8) = v1;
  }
  __syncthreads();

  f32x4 acc[2][4];
#pragma unroll
  for (int i = 0; i < 2; ++i)
#pragma unroll
    for (int jj = 0; jj < 4; ++jj) acc[i][jj] = (f32x4){0.f, 0.f, 0.f, 0.f};

#pragma unroll
  for (int ks = 0; ks < 2; ++ks) {
    bf16x8 bfr[4];
#pragma unroll
    for (int dt = 0; dt < 4; ++dt)
      bfr[dt] = *(const bf16x8*)(ctxd + (dt * 16 + fm) * 72 + ks * 32 + kg * 8);
#pragma unroll
    for (int mi = 0; mi < 2; ++mi) {
      int c = cq * 128 + wave * 32 + mi * 16 + fm;
      bf16x8 af = *(const bf16x8*)(Wot + (size_t)c * 512 + h * 64 + ks * 32 + kg * 8);
#pragma unroll
      for (int dt = 0; dt < 4; ++dt)
        acc[mi][dt] = __builtin_amdgcn_mfma_f32_16x16x32_bf16(af, bfr[dt],
                                                              acc[mi][dt], 0, 0, 0);
    }
  }

  u16* mb = Mt + (size_t)b * 512 * 512;
#pragma unroll
  for (int mi = 0; mi < 2; ++mi)
#pragma unroll
    for (int dt = 0; dt < 4; ++dt)
#pragma unroll
      for (int reg = 0; reg < 4; ++reg) {
        int c = cq * 128 + wave * 32 + mi * 16 + rq * 4 + reg;
        mb[(size_t)c * 512 + h * 64 + dt * 16 + fm] = f2b(acc[mi][dt][reg]);
      }
}

// ---------------------------------------------------------------------------
// Final GEMM: out[b] = q'[b] @ Mt[b]^T + bo. 64x128 tiles, grid 1024.
// Counted-vmcnt 3-buffer pipeline (unchanged).
// ---------------------------------------------------------------------------
__global__ void gemm_out_kernel(const u16* __restrict__ A, const u16* __restrict__ Mt,
                                float* __restrict__ Cout, const float* __restrict__ bias) {
  const int K = 512, N = 512;
  __shared__ u16 smem[18432];  // 3 x (As 4KB + Bs 8KB) = 36 KB
  const int id = blockIdx.x;
  const int tn = id >> 8;                              // [0,4): 128-col tiles
  const int tm = (id & 7) * 32 + ((id >> 3) & 31);     // [0,256): 64-row tiles
  const int tileN = tn * 128;
  const int tileM = tm * 64;
  const u16* Bt = Mt + (size_t)(tm >> 6) * 512 * 512;  // batch = tm/64
  const int t = threadIdx.x;
  const int lane = t & 63;
  const int wave = t >> 6;
  const int mbase = (wave >> 1) * 32;
  const int nbase = (wave & 1) * 64;
  const int fm = lane & 15;
  const int kg = lane >> 4;

  f32x4 acc[2][4];
#pragma unroll
  for (int i = 0; i < 2; ++i)
#pragma unroll
    for (int jj = 0; jj < 4; ++jj) acc[i][jj] = (f32x4){0.f, 0.f, 0.f, 0.f};

  auto stage = [&](int buf, int k0) {
    u16* As = smem + buf * 6144;
    u16* Bs = As + 2048;
    {
      int c = t;                      // A: 64 rows x 4 groups = 256 chunks
      int r = c >> 2;
      int g = (c & 3) ^ ((r >> 1) & 3);
      const u16* ga = A + (size_t)(tileM + r) * K + (k0 + g * 8);
      __builtin_amdgcn_global_load_lds(GLD_AS1(ga), LDS_AS3(As + c * 8), 16, 0, 0);
    }
#pragma unroll
    for (int p = 0; p < 2; ++p) {
      int c = p * 256 + t;            // B: 128 rows x 4 groups = 512 chunks
      int r = c >> 2;
      int g = (c & 3) ^ ((r >> 1) & 3);
      const u16* gb = Bt + (size_t)(tileN + r) * K + (k0 + g * 8);
      __builtin_amdgcn_global_load_lds(GLD_AS1(gb), LDS_AS3(Bs + c * 8), 16, 0, 0);
    }
  };

  stage(0, 0);     // 3 loads/thread per stage
  stage(1, 32);
  stage(2, 64);

  int cur = 0;
  for (int kk = 0; kk < 16; ++kk) {
    if (kk <= 13)      asm volatile("s_waitcnt vmcnt(6)" ::: "memory");
    else if (kk == 14) asm volatile("s_waitcnt vmcnt(3)" ::: "memory");
    else               asm volatile("s_waitcnt vmcnt(0)" ::: "memory");
    __builtin_amdgcn_s_barrier();

    const u16* As = smem + cur * 6144;
    const u16* Bs = As + 2048;
    bf16x8 af[2], bfr[4];
#pragma unroll
    for (int mi = 0; mi < 2; ++mi) {
      int m = mbase + mi * 16 + fm;
      int sg = kg ^ ((m >> 1) & 3);
      af[mi] = *(const bf16x8*)(As + m * 32 + sg * 8);
    }
#pragma unroll
    for (int ni = 0; ni < 4; ++ni) {
      int n = nbase + ni * 16 + fm;
      int sg = kg ^ ((n >> 1) & 3);
      bfr[ni] = *(const bf16x8*)(Bs + n * 32 + sg * 8);
    }
    asm volatile("s_waitcnt lgkmcnt(0)" ::: "memory");
    __builtin_amdgcn_sched_barrier(0);
    __builtin_amdgcn_s_barrier();

    if (kk <= 12) stage(cur, (kk + 3) * 32);

#pragma unroll
    for (int mi = 0; mi < 2; ++mi)
#pragma unroll
      for (int ni = 0; ni < 4; ++ni)
        acc[mi][ni] = __builtin_amdgcn_mfma_f32_16x16x32_bf16(af[mi], bfr[ni],
                                                              acc[mi][ni], 0, 0, 0);
    cur = (cur == 2) ? 0 : cur + 1;
  }

  const int rq = lane >> 4;
#pragma unroll
  for (int mi = 0; mi < 2; ++mi)
#pragma unroll
    for (int ni = 0; ni < 4; ++ni)
#pragma unroll
      for (int reg = 0; reg < 4; ++reg) {
        int gr = tileM + mbase + mi * 16 + rq * 4 + reg;
        int gc = tileN + nbase + ni * 16 + fm;
        Cout[(size_t)gr * N + gc] = acc[mi][ni][reg] + bias[gc];
      }
}

// ---------------------------------------------------------------------------
extern "C" void kernel_launch(void* const* d_in, const int* in_sizes, int n_in,
                              void* d_out, int out_size, void* d_ws, size_t ws_size,
                              hipStream_t stream) {
  const float* x  = (const float*)d_in[0];
  const float* Wq = (const float*)d_in[1];
  const float* Wk = (const float*)d_in[2];
  const float* Wv = (const float*)d_in[3];
  const float* Wo = (const float*)d_in[4];
  const float* bo = (const float*)d_in[5];

  char* w = (char*)d_ws;
  u16* xb   = (u16*)w;    w += (size_t)16384 * 512 * 2;     // 16.8 MB
  u16* Wt   = (u16*)w;    w += (size_t)1536 * 512 * 2;      // 1.6 MB
  u16* Wot  = (u16*)w;    w += (size_t)512 * 512 * 2;       // 0.5 MB
  u16* qbuf = (u16*)w;    w += (size_t)16384 * 512 * 2;     // 16.8 MB
  float* ctxp = (float*)w; w += (size_t)16 * 32 * 4096 * 4; // 8.4 MB (16 partials)
  u16* ctxb = (u16*)w;    w += (size_t)32 * 4096 * 2;       // 0.26 MB
  u16* Mt   = (u16*)w;    w += (size_t)4 * 512 * 512 * 2;   // 2.1 MB

  prep_all_kernel<<<4352, 256, 0, stream>>>(x, Wq, Wk, Wv, Wo, xb, Wt, Wot);
  gemm_qkv_kernel<<<768, 256, 0, stream>>>(xb, Wt, qbuf, ctxp);
  ctx_reduce_kernel<<<128, 256, 0, stream>>>(ctxp, ctxb);
  ctxm_kernel<<<128, 256, 0, stream>>>(ctxb, Wot, Mt);
  gemm_out_kernel<<<1024, 256, 0, stream>>>(qbuf, Mt, (float*)d_out, bo);
}